// Round 1
// baseline (133.444 us; speedup 1.0000x reference)
//
#include <hip/hip_runtime.h>

// FlowRegLoss: B=16, C_img=3, C_flow=2, S=256, P=7 (pad=3), fp32 in/out.
// out = mean_{b,p2,y,x}[ fl * exp(-(im_w*10 + sp_w)) ] with zero-padded
// neighbor shifts. sp_w computed analytically (grid is linspace(-1,1,256)).

#define S_DIM 256
#define PATCH 7
#define PAD 3
#define TILE 16
#define HALO (TILE + 2 * PAD)   // 22
#define LSTRIDE 24              // LDS row stride (floats): 2-way bank aliasing only
#define N_TERMS 51380224.0f     // 16 * 49 * 256 * 256

__global__ void init_out_kernel(float* out) { out[0] = 0.0f; }

__global__ __launch_bounds__(256) void flow_reg_loss_kernel(
    const float* __restrict__ flow,   // [B,2,S,S]
    const float* __restrict__ image,  // [B,3,S,S]
    float* __restrict__ out)
{
    __shared__ float sm[5][HALO][LSTRIDE];   // ch: 0..2 image, 3..4 flow*256
    __shared__ float wave_sums[4];

    const int b   = blockIdx.z;
    const int tx0 = blockIdx.x * TILE;
    const int ty0 = blockIdx.y * TILE;
    const int tid = threadIdx.y * TILE + threadIdx.x;

    const float* img_b = image + (size_t)b * 3 * S_DIM * S_DIM;
    const float* flw_b = flow  + (size_t)b * 2 * S_DIM * S_DIM;

    // ---- stage halo tile into LDS (zero-fill OOB = zero padding) ----
    for (int e = tid; e < HALO * HALO; e += 256) {
        const int ly = e / HALO;
        const int lx = e - ly * HALO;
        const int gy = ty0 - PAD + ly;
        const int gx = tx0 - PAD + lx;
        float i0 = 0.f, i1 = 0.f, i2 = 0.f, f0 = 0.f, f1 = 0.f;
        if ((unsigned)gy < S_DIM && (unsigned)gx < S_DIM) {
            const int g = gy * S_DIM + gx;
            i0 = img_b[0 * S_DIM * S_DIM + g];
            i1 = img_b[1 * S_DIM * S_DIM + g];
            i2 = img_b[2 * S_DIM * S_DIM + g];
            f0 = flw_b[0 * S_DIM * S_DIM + g] * 256.0f;  // flow * img_size
            f1 = flw_b[1 * S_DIM * S_DIM + g] * 256.0f;
        }
        sm[0][ly][lx] = i0;
        sm[1][ly][lx] = i1;
        sm[2][ly][lx] = i2;
        sm[3][ly][lx] = f0;
        sm[4][ly][lx] = f1;
    }
    __syncthreads();

    // ---- per-pixel accumulation over the 7x7 window ----
    const int lx = threadIdx.x, ly = threadIdx.y;
    const int x = tx0 + lx, y = ty0 + ly;
    const int cy = ly + PAD, cx = lx + PAD;

    const float ic0 = sm[0][cy][cx], ic1 = sm[1][cy][cx], ic2 = sm[2][cy][cx];
    const float fc0 = sm[3][cy][cx], fc1 = sm[4][cy][cx];

    const float step = 2.0f / 255.0f;
    const float gyc = -1.0f + step * (float)y;
    const float gxc = -1.0f + step * (float)x;
    const float g2c = gyc * gyc + gxc * gxc;   // sp_w when neighbor is OOB (grid_nb = 0)
    const float K2 = step * step;

    float acc = 0.0f;
#pragma unroll
    for (int dy = -PAD; dy <= PAD; ++dy) {
#pragma unroll
        for (int dx = -PAD; dx <= PAD; ++dx) {
            const int ny = cy + dy, nx = cx + dx;
            const float n0 = sm[0][ny][nx];
            const float n1 = sm[1][ny][nx];
            const float n2 = sm[2][ny][nx];
            const float m0 = sm[3][ny][nx];
            const float m1 = sm[4][ny][nx];

            const float d0 = ic0 - n0, d1 = ic1 - n1, d2 = ic2 - n2;
            const float imw = d0 * d0 + d1 * d1 + d2 * d2;
            const float e0 = m0 - fc0, e1 = m1 - fc1;
            const float fl2 = e0 * e0 + e1 * e1;

            const bool inb = ((unsigned)(y + dy) < S_DIM) && ((unsigned)(x + dx) < S_DIM);
            const float spw = inb ? (K2 * (float)(dy * dy + dx * dx)) : g2c;

            acc += fl2 * __expf(-(imw * 10.0f + spw));
        }
    }

    // ---- block reduction: wave shuffle then cross-wave via LDS ----
#pragma unroll
    for (int off = 32; off > 0; off >>= 1)
        acc += __shfl_down(acc, off, 64);
    if ((tid & 63) == 0) wave_sums[tid >> 6] = acc;
    __syncthreads();
    if (tid == 0) {
        const float s = wave_sums[0] + wave_sums[1] + wave_sums[2] + wave_sums[3];
        atomicAdd(out, s * (1.0f / N_TERMS));
    }
}

extern "C" void kernel_launch(void* const* d_in, const int* in_sizes, int n_in,
                              void* d_out, int out_size, void* d_ws, size_t ws_size,
                              hipStream_t stream) {
    const float* flow  = (const float*)d_in[0];
    const float* image = (const float*)d_in[1];
    float* out = (float*)d_out;

    init_out_kernel<<<1, 1, 0, stream>>>(out);

    dim3 grid(S_DIM / TILE, S_DIM / TILE, 16);  // 16x16 tiles x B
    dim3 block(TILE, TILE);
    flow_reg_loss_kernel<<<grid, block, 0, stream>>>(flow, image, out);
}

// Round 2
// 97.571 us; speedup vs baseline: 1.3677x; 1.3677x over previous
//
#include <hip/hip_runtime.h>

// FlowRegLoss: B=16, C_img=3, C_flow=2, S=256, P=7 (pad=3), fp32 in/out.
// out = mean_{b,p2,y,x}[ fl * exp(-(im_w*10 + sp_w)) ], zero-padded shifts,
// sp_w analytic (grid = linspace(-1,1,256)).
//
// R1: x-coarsening (4 px/thread) + ds_read_b128 row loads. LDS reads drop
// from 245 scalar/pixel to ~26 b128-lane-reads/pixel — LDS pipe was the R0
// bottleneck (38 µs of ds_read_b32 issue at 5.8 cyc each).

#define S_DIM 256
#define PAD 3
#define TILE_X 64
#define TILE_Y 16
#define CX 4
#define QX (TILE_X / CX)          // 16 thread-quads in x
#define HALO_X (TILE_X + 2*PAD)   // 70
#define HALO_Y (TILE_Y + 2*PAD)   // 22
#define LSTRIDE 72                // floats; 288 B row: 16B-aligned, mult of 4 floats
#define N_TERMS 51380224.0f       // 16 * 49 * 256 * 256

__global__ void init_out_kernel(float* out) { out[0] = 0.0f; }

__global__ __launch_bounds__(256) void flow_reg_loss_kernel(
    const float* __restrict__ flow,   // [B,2,S,S]
    const float* __restrict__ image,  // [B,3,S,S]
    float* __restrict__ out)
{
    __shared__ float sm[5][HALO_Y][LSTRIDE];   // ch: 0..2 image, 3..4 flow*256
    __shared__ float wave_sums[4];

    const int b   = blockIdx.z;
    const int tx0 = blockIdx.x * TILE_X;
    const int ty0 = blockIdx.y * TILE_Y;
    const int tid = threadIdx.y * QX + threadIdx.x;

    const float* img_b = image + (size_t)b * 3 * S_DIM * S_DIM;
    const float* flw_b = flow  + (size_t)b * 2 * S_DIM * S_DIM;

    // ---- stage halo tile into LDS (zero-fill OOB = zero padding) ----
    for (int e = tid; e < HALO_Y * HALO_X; e += 256) {
        const int ly = e / HALO_X;
        const int lx = e - ly * HALO_X;
        const int gy = ty0 - PAD + ly;
        const int gx = tx0 - PAD + lx;
        float i0 = 0.f, i1 = 0.f, i2 = 0.f, f0 = 0.f, f1 = 0.f;
        if ((unsigned)gy < S_DIM && (unsigned)gx < S_DIM) {
            const int g = gy * S_DIM + gx;
            i0 = img_b[0 * S_DIM * S_DIM + g];
            i1 = img_b[1 * S_DIM * S_DIM + g];
            i2 = img_b[2 * S_DIM * S_DIM + g];
            f0 = flw_b[0 * S_DIM * S_DIM + g] * 256.0f;   // flow * img_size
            f1 = flw_b[1 * S_DIM * S_DIM + g] * 256.0f;
        }
        sm[0][ly][lx] = i0;
        sm[1][ly][lx] = i1;
        sm[2][ly][lx] = i2;
        sm[3][ly][lx] = f0;
        sm[4][ly][lx] = f1;
    }
    __syncthreads();

    // ---- each thread: CX=4 consecutive x pixels at row ty ----
    const int qx = threadIdx.x;     // 0..15
    const int ty = threadIdx.y;     // 0..15
    const int cy = ty + PAD;
    const int xb = qx * CX;         // halo-x of leftmost tap (= center-3 of pixel 0)
    const int y  = ty0 + ty;
    const int x0 = tx0 + xb;        // global x of pixel i=0

    // center values (one-time scalar reads)
    float ic0[CX], ic1[CX], ic2[CX], fc0[CX], fc1[CX];
#pragma unroll
    for (int i = 0; i < CX; ++i) {
        ic0[i] = sm[0][cy][xb + PAD + i];
        ic1[i] = sm[1][cy][xb + PAD + i];
        ic2[i] = sm[2][cy][xb + PAD + i];
        fc0[i] = sm[3][cy][xb + PAD + i];
        fc1[i] = sm[4][cy][xb + PAD + i];
    }

    const float step = 2.0f / 255.0f;
    const float K2 = step * step;
    const float gyc = -1.0f + step * (float)y;
    float g2c[CX];                   // sp_w when neighbor OOB (grid_nb = 0)
#pragma unroll
    for (int i = 0; i < CX; ++i) {
        const float gxc = -1.0f + step * (float)(x0 + i);
        g2c[i] = gyc * gyc + gxc * gxc;
    }

    float acc[CX] = {0.f, 0.f, 0.f, 0.f};

#pragma unroll
    for (int dy = -PAD; dy <= PAD; ++dy) {
        const int ny = cy + dy;
        const bool yin = (unsigned)(y + dy) < S_DIM;

        // 15 x ds_read_b128: 12 floats per channel row (taps j=0..9 used)
        float r[5][12];
#pragma unroll
        for (int c = 0; c < 5; ++c) {
            const float4 a  = *(const float4*)&sm[c][ny][xb];
            const float4 b4 = *(const float4*)&sm[c][ny][xb + 4];
            const float4 c4 = *(const float4*)&sm[c][ny][xb + 8];
            r[c][0] = a.x;  r[c][1] = a.y;  r[c][2]  = a.z;  r[c][3]  = a.w;
            r[c][4] = b4.x; r[c][5] = b4.y; r[c][6]  = b4.z; r[c][7]  = b4.w;
            r[c][8] = c4.x; r[c][9] = c4.y; r[c][10] = c4.z; r[c][11] = c4.w;
        }

#pragma unroll
        for (int dx = -PAD; dx <= PAD; ++dx) {
            const float spw_in = K2 * (float)(dy * dy + dx * dx);
#pragma unroll
            for (int i = 0; i < CX; ++i) {
                const int j = i + dx + PAD;          // 0..9, constant after unroll
                const float d0 = ic0[i] - r[0][j];
                const float d1 = ic1[i] - r[1][j];
                const float d2 = ic2[i] - r[2][j];
                const float imw = d0 * d0 + d1 * d1 + d2 * d2;
                const float e0 = r[3][j] - fc0[i];
                const float e1 = r[4][j] - fc1[i];
                const float fl2 = e0 * e0 + e1 * e1;
                const bool inb = yin && ((unsigned)(x0 + i + dx) < S_DIM);
                const float spw = inb ? spw_in : g2c[i];
                acc[i] += fl2 * __expf(-(imw * 10.0f + spw));
            }
        }
    }

    // ---- block reduction: wave shuffle then cross-wave via LDS ----
    float acc_all = (acc[0] + acc[1]) + (acc[2] + acc[3]);
#pragma unroll
    for (int off = 32; off > 0; off >>= 1)
        acc_all += __shfl_down(acc_all, off, 64);
    if ((tid & 63) == 0) wave_sums[tid >> 6] = acc_all;
    __syncthreads();
    if (tid == 0) {
        const float s = wave_sums[0] + wave_sums[1] + wave_sums[2] + wave_sums[3];
        atomicAdd(out, s * (1.0f / N_TERMS));
    }
}

extern "C" void kernel_launch(void* const* d_in, const int* in_sizes, int n_in,
                              void* d_out, int out_size, void* d_ws, size_t ws_size,
                              hipStream_t stream) {
    const float* flow  = (const float*)d_in[0];
    const float* image = (const float*)d_in[1];
    float* out = (float*)d_out;

    init_out_kernel<<<1, 1, 0, stream>>>(out);

    dim3 grid(S_DIM / TILE_X, S_DIM / TILE_Y, 16);   // 4 x 16 x 16 = 1024 blocks
    dim3 block(QX, TILE_Y);                           // 16 x 16 = 256 threads
    flow_reg_loss_kernel<<<grid, block, 0, stream>>>(flow, image, out);
}

// Round 3
// 91.153 us; speedup vs baseline: 1.4640x; 1.0704x over previous
//
#include <hip/hip_runtime.h>

// FlowRegLoss: B=16, C_img=3, C_flow=2, S=256, P=7 (pad=3), fp32 in/out.
// out = mean_{b,p2,y,x}[ fl * exp(-(im_w*10 + sp_w)) ], zero-padded shifts,
// sp_w analytic (grid = linspace(-1,1,256)).
//
// R2: pair symmetry. term(p,q)==term(q,p) for in-bounds q; center tap is 0
// (fl=0); all OOB taps of p contribute the identical t_oob — collapsed to an
// analytic count n_oob(x,y). So: 24-tap half-window x2 + n_oob*t_oob.
// Halves taps AND LDS rows (no top halo).

#define S_DIM 256
#define PAD 3
#define TILE_X 64
#define TILE_Y 16
#define CX 4
#define QX (TILE_X / CX)            // 16 threads in x
#define HALO_X (TILE_X + 2*PAD)     // 70
#define HALO_Y (TILE_Y + PAD)       // 19 (half-window: dy >= 0 only)
#define LSTRIDE 72                  // floats; 288 B rows, 16B-aligned
#define N_TERMS 51380224.0f         // 16 * 49 * 256 * 256

__global__ void init_out_kernel(float* out) { out[0] = 0.0f; }

__global__ __launch_bounds__(256) void flow_reg_loss_kernel(
    const float* __restrict__ flow,   // [B,2,S,S]
    const float* __restrict__ image,  // [B,3,S,S]
    float* __restrict__ out)
{
    __shared__ float sm[5][HALO_Y][LSTRIDE];   // ch: 0..2 image, 3..4 flow*256
    __shared__ float wave_sums[4];

    const int b   = blockIdx.z;
    const int tx0 = blockIdx.x * TILE_X;
    const int ty0 = blockIdx.y * TILE_Y;
    const int tid = threadIdx.y * QX + threadIdx.x;

    const float* img_b = image + (size_t)b * 3 * S_DIM * S_DIM;
    const float* flw_b = flow  + (size_t)b * 2 * S_DIM * S_DIM;

    // ---- stage tile + bottom/left/right halo (zero-fill OOB) ----
    for (int e = tid; e < HALO_Y * HALO_X; e += 256) {
        const int ly = e / HALO_X;
        const int lx = e - ly * HALO_X;
        const int gy = ty0 + ly;            // rows ty0 .. ty0+18 (no top halo)
        const int gx = tx0 - PAD + lx;
        float i0 = 0.f, i1 = 0.f, i2 = 0.f, f0 = 0.f, f1 = 0.f;
        if ((unsigned)gy < S_DIM && (unsigned)gx < S_DIM) {
            const int g = gy * S_DIM + gx;
            i0 = img_b[0 * S_DIM * S_DIM + g];
            i1 = img_b[1 * S_DIM * S_DIM + g];
            i2 = img_b[2 * S_DIM * S_DIM + g];
            f0 = flw_b[0 * S_DIM * S_DIM + g] * 256.0f;   // flow * img_size
            f1 = flw_b[1 * S_DIM * S_DIM + g] * 256.0f;
        }
        sm[0][ly][lx] = i0;
        sm[1][ly][lx] = i1;
        sm[2][ly][lx] = i2;
        sm[3][ly][lx] = f0;
        sm[4][ly][lx] = f1;
    }
    __syncthreads();

    // ---- each thread: CX=4 consecutive x pixels at row ty ----
    const int qx = threadIdx.x;     // 0..15
    const int ty = threadIdx.y;     // 0..15 (center row index in sm)
    const int xb = qx * CX;         // LDS col of leftmost tap (center-3 of px 0)
    const int y  = ty0 + ty;
    const int x0 = tx0 + xb;        // global x of pixel i=0 center

    const float step = 2.0f / 255.0f;
    const float K2 = step * step;

    float acc = 0.0f;       // sum of half-window pair terms (x2 at the end)
    float ic0[CX], ic1[CX], ic2[CX], fc0[CX], fc1[CX];

    // ---- dy = 0 row: centers + right-only taps, from 3 b128 per channel ----
    {
        float r[5][12];
#pragma unroll
        for (int c = 0; c < 5; ++c) {
            const float4 a  = *(const float4*)&sm[c][ty][xb];
            const float4 b4 = *(const float4*)&sm[c][ty][xb + 4];
            const float4 c4 = *(const float4*)&sm[c][ty][xb + 8];
            r[c][0] = a.x;  r[c][1] = a.y;  r[c][2]  = a.z;  r[c][3]  = a.w;
            r[c][4] = b4.x; r[c][5] = b4.y; r[c][6]  = b4.z; r[c][7]  = b4.w;
            r[c][8] = c4.x; r[c][9] = c4.y; r[c][10] = c4.z; r[c][11] = c4.w;
        }
#pragma unroll
        for (int i = 0; i < CX; ++i) {
            ic0[i] = r[0][3 + i]; ic1[i] = r[1][3 + i]; ic2[i] = r[2][3 + i];
            fc0[i] = r[3][3 + i]; fc1[i] = r[4][3 + i];
        }
#pragma unroll
        for (int dx = 1; dx <= PAD; ++dx) {
            const float spw_in = K2 * (float)(dx * dx);
#pragma unroll
            for (int i = 0; i < CX; ++i) {
                const int j = i + dx + 3;                 // 4..9
                const float d0 = ic0[i] - r[0][j];
                const float d1 = ic1[i] - r[1][j];
                const float d2 = ic2[i] - r[2][j];
                const float imw = d0 * d0 + d1 * d1 + d2 * d2;
                const float e0 = r[3][j] - fc0[i];
                const float e1 = r[4][j] - fc1[i];
                const float fl2 = e0 * e0 + e1 * e1;
                const float w = ((unsigned)(x0 + i + dx) < S_DIM) ? 1.0f : 0.0f;
                acc += (w * fl2) * __expf(-(imw * 10.0f + spw_in));
            }
        }
    }

    // ---- dy = 1..3 rows: full 7 dx taps ----
#pragma unroll
    for (int dy = 1; dy <= PAD; ++dy) {
        const int ny = ty + dy;
        const bool yin = (y + dy) < S_DIM;
        float r[5][12];
#pragma unroll
        for (int c = 0; c < 5; ++c) {
            const float4 a  = *(const float4*)&sm[c][ny][xb];
            const float4 b4 = *(const float4*)&sm[c][ny][xb + 4];
            const float4 c4 = *(const float4*)&sm[c][ny][xb + 8];
            r[c][0] = a.x;  r[c][1] = a.y;  r[c][2]  = a.z;  r[c][3]  = a.w;
            r[c][4] = b4.x; r[c][5] = b4.y; r[c][6]  = b4.z; r[c][7]  = b4.w;
            r[c][8] = c4.x; r[c][9] = c4.y; r[c][10] = c4.z; r[c][11] = c4.w;
        }
#pragma unroll
        for (int dx = -PAD; dx <= PAD; ++dx) {
            const float spw_in = K2 * (float)(dy * dy + dx * dx);
#pragma unroll
            for (int i = 0; i < CX; ++i) {
                const int j = i + dx + 3;                 // 0..9
                const float d0 = ic0[i] - r[0][j];
                const float d1 = ic1[i] - r[1][j];
                const float d2 = ic2[i] - r[2][j];
                const float imw = d0 * d0 + d1 * d1 + d2 * d2;
                const float e0 = r[3][j] - fc0[i];
                const float e1 = r[4][j] - fc1[i];
                const float fl2 = e0 * e0 + e1 * e1;
                const float w = (yin && (unsigned)(x0 + i + dx) < S_DIM) ? 1.0f : 0.0f;
                acc += (w * fl2) * __expf(-(imw * 10.0f + spw_in));
            }
        }
    }

    // ---- OOB taps: n_oob(x,y) identical terms per pixel ----
    const int ny_in = 7 - max(0, 3 - y) - max(0, y - (S_DIM - 1 - 3));
    const float gyc = -1.0f + step * (float)y;
    float oob = 0.0f;
#pragma unroll
    for (int i = 0; i < CX; ++i) {
        const int xg = x0 + i;
        const int nx_in = 7 - max(0, 3 - xg) - max(0, xg - (S_DIM - 1 - 3));
        const float n_oob = (float)(49 - ny_in * nx_in);
        const float gxc = -1.0f + step * (float)xg;
        const float g2c = gyc * gyc + gxc * gxc;
        const float imw_c = ic0[i] * ic0[i] + ic1[i] * ic1[i] + ic2[i] * ic2[i];
        const float fl_c  = fc0[i] * fc0[i] + fc1[i] * fc1[i];
        oob += (n_oob * fl_c) * __expf(-(imw_c * 10.0f + g2c));
    }

    // ---- block reduction: wave shuffle then cross-wave via LDS ----
    float acc_all = 2.0f * acc + oob;
#pragma unroll
    for (int off = 32; off > 0; off >>= 1)
        acc_all += __shfl_down(acc_all, off, 64);
    if ((tid & 63) == 0) wave_sums[tid >> 6] = acc_all;
    __syncthreads();
    if (tid == 0) {
        const float s = wave_sums[0] + wave_sums[1] + wave_sums[2] + wave_sums[3];
        atomicAdd(out, s * (1.0f / N_TERMS));
    }
}

extern "C" void kernel_launch(void* const* d_in, const int* in_sizes, int n_in,
                              void* d_out, int out_size, void* d_ws, size_t ws_size,
                              hipStream_t stream) {
    const float* flow  = (const float*)d_in[0];
    const float* image = (const float*)d_in[1];
    float* out = (float*)d_out;

    init_out_kernel<<<1, 1, 0, stream>>>(out);

    dim3 grid(S_DIM / TILE_X, S_DIM / TILE_Y, 16);   // 4 x 16 x 16 = 1024 blocks
    dim3 block(QX, TILE_Y);                           // 16 x 16 = 256 threads
    flow_reg_loss_kernel<<<grid, block, 0, stream>>>(flow, image, out);
}

// Round 4
// 84.932 us; speedup vs baseline: 1.5712x; 1.0732x over previous
//
#include <hip/hip_runtime.h>

// FlowRegLoss: B=16, C_img=3, C_flow=2, S=256, P=7 (pad=3), fp32 in/out.
// out = mean_{b,p2,y,x}[ fl * exp(-(im_w*10 + sp_w)) ], zero-padded shifts,
// sp_w analytic (grid = linspace(-1,1,256)).
//
// R3: kill the stage->barrier->compute phase structure (R2 was latency-bound:
// all pipes ~6 us yet kernel ~26 us). Direct global reads via raw buffer
// loads (SRD bounds-check: true OOB returns 0, no fault; in-plane wraps are
// finite garbage killed by the w=0 gate). No LDS staging, no __syncthreads
// in the main path, per-block partials -> tiny reduce kernel (no atomic tail,
// no init kernel). Flow*256 folded into final scale (x65536).
// Pair symmetry from R2 kept: 24-tap half-window x2 + analytic OOB term.

#define S_DIM 256
#define LOG2E 1.4426950408889634f
#define C10L2E (-14.426950408889634f)      // -10*log2(e)
#define N_TERMS 51380224.0f                 // 16 * 49 * 256 * 256
#define FINAL_SCALE (65536.0f / N_TERMS)    // flow*256 -> fl2*65536, folded here

typedef float v4f __attribute__((ext_vector_type(4)));
typedef int   v4i __attribute__((ext_vector_type(4)));

__device__ v4f llvm_amdgcn_raw_buffer_load_v4f32(v4i rsrc, int voffset,
                                                 int soffset, int aux)
    __asm("llvm.amdgcn.raw.buffer.load.v4f32");

__device__ inline v4i make_srd(const void* p, unsigned bytes) {
    union { v4i v; unsigned u[4]; } s;
    s.u[0] = (unsigned)(unsigned long long)p;
    s.u[1] = (unsigned)(((unsigned long long)p) >> 32);   // stride=0
    s.u[2] = bytes;                                       // num_records (bytes)
    s.u[3] = 0x00020000u;                                 // raw dword access
    return s.v;
}

__global__ __launch_bounds__(256, 4) void flow_reg_loss_kernel(
    const float* __restrict__ flow,   // [B,2,S,S]
    const float* __restrict__ image,  // [B,3,S,S]
    float* __restrict__ partial)      // [1024] block partials (in d_ws)
{
    __shared__ float wave_sums[4];

    const int lane = threadIdx.x;           // 0..63
    const int wy   = threadIdx.y;           // 0..3 (wave index)
    const int y    = blockIdx.x * 4 + wy;   // row
    const int b    = blockIdx.z;            // batch
    const int x0   = lane * 4;              // 4 px per thread, 16B-aligned

    const v4i srdI = make_srd(image, 16u * 3u * 65536u * 4u);
    const v4i srdF = make_srd(flow,  16u * 2u * 65536u * 4u);

    const int rowx = x0 * 4 - 12;           // byte offset of float x0-3 in a row
    const int ib = b * 786432;              // batch stride, image (3*65536*4)
    const int fb = b * 524288;              // batch stride, flow  (2*65536*4)

    const float step = 2.0f / 255.0f;
    const float K2L2E = step * step * LOG2E;

    float acc = 0.0f;
    float ic0[4], ic1[4], ic2[4], fc0[4], fc1[4];

#define LOAD_ROW(r, yy)                                                        \
    do {                                                                       \
        const int ro = (yy) * 1024 + rowx;                                     \
        _Pragma("unroll")                                                      \
        for (int c = 0; c < 3; ++c) {                                          \
            const int v = ib + c * 262144 + ro;                                \
            const v4f a  = llvm_amdgcn_raw_buffer_load_v4f32(srdI, v, 0, 0);   \
            const v4f b4 = llvm_amdgcn_raw_buffer_load_v4f32(srdI, v, 16, 0);  \
            const v4f c4 = llvm_amdgcn_raw_buffer_load_v4f32(srdI, v, 32, 0);  \
            r[c][0] = a.x;  r[c][1] = a.y;  r[c][2]  = a.z;  r[c][3]  = a.w;   \
            r[c][4] = b4.x; r[c][5] = b4.y; r[c][6]  = b4.z; r[c][7]  = b4.w;  \
            r[c][8] = c4.x; r[c][9] = c4.y; r[c][10] = c4.z; r[c][11] = c4.w;  \
        }                                                                      \
        _Pragma("unroll")                                                      \
        for (int c = 0; c < 2; ++c) {                                          \
            const int v = fb + c * 262144 + ro;                                \
            const v4f a  = llvm_amdgcn_raw_buffer_load_v4f32(srdF, v, 0, 0);   \
            const v4f b4 = llvm_amdgcn_raw_buffer_load_v4f32(srdF, v, 16, 0);  \
            const v4f c4 = llvm_amdgcn_raw_buffer_load_v4f32(srdF, v, 32, 0);  \
            r[3+c][0] = a.x;  r[3+c][1] = a.y;  r[3+c][2]  = a.z;              \
            r[3+c][3] = a.w;  r[3+c][4] = b4.x; r[3+c][5]  = b4.y;             \
            r[3+c][6] = b4.z; r[3+c][7] = b4.w; r[3+c][8]  = c4.x;             \
            r[3+c][9] = c4.y; r[3+c][10] = c4.z; r[3+c][11] = c4.w;            \
        }                                                                      \
    } while (0)

    // ---- dy = 0 row: centers + right-only taps ----
    {
        float r[5][12];
        LOAD_ROW(r, y);
#pragma unroll
        for (int i = 0; i < 4; ++i) {
            ic0[i] = r[0][3 + i]; ic1[i] = r[1][3 + i]; ic2[i] = r[2][3 + i];
            fc0[i] = r[3][3 + i]; fc1[i] = r[4][3 + i];
        }
#pragma unroll
        for (int dx = 1; dx <= 3; ++dx) {
            const float c2 = -K2L2E * (float)(dx * dx);
#pragma unroll
            for (int i = 0; i < 4; ++i) {
                const int j = i + dx + 3;
                const float d0 = ic0[i] - r[0][j];
                const float d1 = ic1[i] - r[1][j];
                const float d2 = ic2[i] - r[2][j];
                const float imw = d0 * d0 + d1 * d1 + d2 * d2;
                const float e0 = r[3][j] - fc0[i];
                const float e1 = r[4][j] - fc1[i];
                const float fl2 = e0 * e0 + e1 * e1;
                const float w = ((unsigned)(x0 + i + dx) < S_DIM) ? 1.0f : 0.0f;
                acc += (w * fl2) * __builtin_amdgcn_exp2f(fmaf(imw, C10L2E, c2));
            }
        }
    }

    // ---- dy = 1..3 rows: full 7 dx taps ----
#pragma unroll
    for (int dy = 1; dy <= 3; ++dy) {
        float r[5][12];
        LOAD_ROW(r, y + dy);
        const bool yin = (y + dy) < S_DIM;
#pragma unroll
        for (int dx = -3; dx <= 3; ++dx) {
            const float c2 = -K2L2E * (float)(dy * dy + dx * dx);
#pragma unroll
            for (int i = 0; i < 4; ++i) {
                const int j = i + dx + 3;
                const float d0 = ic0[i] - r[0][j];
                const float d1 = ic1[i] - r[1][j];
                const float d2 = ic2[i] - r[2][j];
                const float imw = d0 * d0 + d1 * d1 + d2 * d2;
                const float e0 = r[3][j] - fc0[i];
                const float e1 = r[4][j] - fc1[i];
                const float fl2 = e0 * e0 + e1 * e1;
                const float w = (yin && (unsigned)(x0 + i + dx) < S_DIM) ? 1.0f : 0.0f;
                acc += (w * fl2) * __builtin_amdgcn_exp2f(fmaf(imw, C10L2E, c2));
            }
        }
    }

    // ---- OOB taps: n_oob(x,y) identical terms per pixel ----
    const int ny_in = 7 - max(0, 3 - y) - max(0, y - (S_DIM - 1 - 3));
    const float gyc = -1.0f + step * (float)y;
    float oob = 0.0f;
#pragma unroll
    for (int i = 0; i < 4; ++i) {
        const int xg = x0 + i;
        const int nx_in = 7 - max(0, 3 - xg) - max(0, xg - (S_DIM - 1 - 3));
        const float n_oob = (float)(49 - ny_in * nx_in);
        const float gxc = -1.0f + step * (float)xg;
        const float g2c = gyc * gyc + gxc * gxc;
        const float imw_c = ic0[i] * ic0[i] + ic1[i] * ic1[i] + ic2[i] * ic2[i];
        const float fl_c  = fc0[i] * fc0[i] + fc1[i] * fc1[i];
        oob += (n_oob * fl_c) *
               __builtin_amdgcn_exp2f(fmaf(imw_c, C10L2E, -g2c * LOG2E));
    }

    // ---- block reduction -> per-block partial ----
    float acc_all = 2.0f * acc + oob;
#pragma unroll
    for (int off = 32; off > 0; off >>= 1)
        acc_all += __shfl_down(acc_all, off, 64);
    if (lane == 0) wave_sums[wy] = acc_all;
    __syncthreads();
    if (lane == 0 && wy == 0) {
        partial[blockIdx.z * gridDim.x + blockIdx.x] =
            (wave_sums[0] + wave_sums[1]) + (wave_sums[2] + wave_sums[3]);
    }
}

__global__ __launch_bounds__(256) void reduce_kernel(
    const float* __restrict__ partial, float* __restrict__ out)
{
    __shared__ float wave_sums[4];
    const int t = threadIdx.x;
    const v4f* p4 = (const v4f*)partial;           // 1024 floats = 256 v4f
    const v4f v = p4[t];
    float s = (v.x + v.y) + (v.z + v.w);
#pragma unroll
    for (int off = 32; off > 0; off >>= 1)
        s += __shfl_down(s, off, 64);
    if ((t & 63) == 0) wave_sums[t >> 6] = s;
    __syncthreads();
    if (t == 0) {
        out[0] = ((wave_sums[0] + wave_sums[1]) + (wave_sums[2] + wave_sums[3]))
                 * FINAL_SCALE;
    }
}

extern "C" void kernel_launch(void* const* d_in, const int* in_sizes, int n_in,
                              void* d_out, int out_size, void* d_ws, size_t ws_size,
                              hipStream_t stream) {
    const float* flow  = (const float*)d_in[0];
    const float* image = (const float*)d_in[1];
    float* out = (float*)d_out;
    float* partial = (float*)d_ws;

    dim3 grid(64, 1, 16);     // 64 row-groups x 16 batches = 1024 blocks
    dim3 block(64, 4);        // one wave per row, 4 rows per block
    flow_reg_loss_kernel<<<grid, block, 0, stream>>>(flow, image, partial);
    reduce_kernel<<<1, 256, 0, stream>>>(partial, out);
}

// Round 5
// 83.354 us; speedup vs baseline: 1.6009x; 1.0189x over previous
//
#include <hip/hip_runtime.h>

// FlowRegLoss: B=16, C_img=3, C_flow=2, S=256, P=7 (pad=3), fp32 in/out.
// out = mean_{b,p2,y,x}[ fl * exp(-(im_w*10 + sp_w)) ], zero-padded shifts,
// sp_w analytic (grid = linspace(-1,1,256)).
//
// R4: CY=2 y-coarsening (each row loaded once, not 4x: 75 loads/8px vs
// 60/4px) + rolling A/B register double-buffer so next row's buffer loads
// are in flight while current row's taps compute. launch_bounds(256,2)
// lifts the 128-VGPR cap that forced R3 into load->vmcnt(0)->compute
// serialization. Pair symmetry kept: half-window x2 + analytic OOB term.

#define S_DIM 256
#define LOG2E 1.4426950408889634f
#define C10L2E (-14.426950408889634f)      // -10*log2(e)
#define N_TERMS 51380224.0f                 // 16 * 49 * 256 * 256
#define FINAL_SCALE (65536.0f / N_TERMS)    // flow*256 -> fl2*65536, folded here

typedef float v4f __attribute__((ext_vector_type(4)));
typedef int   v4i __attribute__((ext_vector_type(4)));

__device__ v4f llvm_amdgcn_raw_buffer_load_v4f32(v4i rsrc, int voffset,
                                                 int soffset, int aux)
    __asm("llvm.amdgcn.raw.buffer.load.v4f32");

__device__ inline v4i make_srd(const void* p, unsigned bytes) {
    union { v4i v; unsigned u[4]; } s;
    s.u[0] = (unsigned)(unsigned long long)p;
    s.u[1] = (unsigned)(((unsigned long long)p) >> 32);   // stride=0
    s.u[2] = bytes;                                       // num_records (bytes)
    s.u[3] = 0x00020000u;                                 // raw dword access
    return s.v;
}

__global__ __launch_bounds__(256, 2) void flow_reg_loss_kernel(
    const float* __restrict__ flow,   // [B,2,S,S]
    const float* __restrict__ image,  // [B,3,S,S]
    float* __restrict__ partial)      // [512] block partials (in d_ws)
{
    __shared__ float wave_sums[4];

    const int lane = threadIdx.x;                 // 0..63
    const int wv   = threadIdx.y;                 // 0..3
    const int y0   = (blockIdx.x * 4 + wv) * 2;   // center row pair: y0, y0+1
    const int b    = blockIdx.z;
    const int x0   = lane * 4;                    // 4 px per thread in x

    const v4i srdI = make_srd(image, 16u * 3u * 65536u * 4u);
    const v4i srdF = make_srd(flow,  16u * 2u * 65536u * 4u);

    const int rowx = x0 * 4 - 12;     // byte offset of float x0-3 in a row
    const int ib = b * 786432;        // batch stride bytes, image
    const int fb = b * 524288;        // batch stride bytes, flow

    const float step = 2.0f / 255.0f;
    const float K2L2E = step * step * LOG2E;

#define LOAD_ROW(r, yy)                                                        \
    do {                                                                       \
        const int ro = (yy) * 1024 + rowx;                                     \
        _Pragma("unroll")                                                      \
        for (int c = 0; c < 3; ++c) {                                          \
            const int v = ib + c * 262144 + ro;                                \
            const v4f a  = llvm_amdgcn_raw_buffer_load_v4f32(srdI, v, 0, 0);   \
            const v4f b4 = llvm_amdgcn_raw_buffer_load_v4f32(srdI, v, 16, 0);  \
            const v4f c4 = llvm_amdgcn_raw_buffer_load_v4f32(srdI, v, 32, 0);  \
            r[c][0] = a.x;  r[c][1] = a.y;  r[c][2]  = a.z;  r[c][3]  = a.w;   \
            r[c][4] = b4.x; r[c][5] = b4.y; r[c][6]  = b4.z; r[c][7]  = b4.w;  \
            r[c][8] = c4.x; r[c][9] = c4.y; r[c][10] = c4.z; r[c][11] = c4.w;  \
        }                                                                      \
        _Pragma("unroll")                                                      \
        for (int c = 0; c < 2; ++c) {                                          \
            const int v = fb + c * 262144 + ro;                                \
            const v4f a  = llvm_amdgcn_raw_buffer_load_v4f32(srdF, v, 0, 0);   \
            const v4f b4 = llvm_amdgcn_raw_buffer_load_v4f32(srdF, v, 16, 0);  \
            const v4f c4 = llvm_amdgcn_raw_buffer_load_v4f32(srdF, v, 32, 0);  \
            r[3+c][0] = a.x;  r[3+c][1] = a.y;  r[3+c][2]  = a.z;              \
            r[3+c][3] = a.w;  r[3+c][4] = b4.x; r[3+c][5]  = b4.y;             \
            r[3+c][6] = b4.z; r[3+c][7] = b4.w; r[3+c][8]  = c4.x;             \
            r[3+c][9] = c4.y; r[3+c][10] = c4.z; r[3+c][11] = c4.w;            \
        }                                                                      \
    } while (0)

    float A[5][12], B[5][12];
    LOAD_ROW(A, y0);          // row y0
    LOAD_ROW(B, y0 + 1);      // row y0+1 (in flight while A's taps compute)

    // center values for the two center rows
    float ic0[2][4], ic1[2][4], ic2[2][4], fc0[2][4], fc1[2][4];
    float acc = 0.0f;

    // pair terms between center row cr and tap row r (global row y0+ro)
    auto tap_row = [&](int cr, const float (&r)[5][12], int dy, int dx0,
                       bool yin) {
#pragma unroll
        for (int dx = dx0; dx <= 3; ++dx) {
            const float c2 = -K2L2E * (float)(dy * dy + dx * dx);
#pragma unroll
            for (int i = 0; i < 4; ++i) {
                const int j = i + dx + 3;
                const float d0 = ic0[cr][i] - r[0][j];
                const float d1 = ic1[cr][i] - r[1][j];
                const float d2 = ic2[cr][i] - r[2][j];
                const float imw = d0 * d0 + d1 * d1 + d2 * d2;
                const float e0 = r[3][j] - fc0[cr][i];
                const float e1 = r[4][j] - fc1[cr][i];
                const float fl2 = e0 * e0 + e1 * e1;
                const float wq =
                    (yin && (unsigned)(x0 + i + dx) < S_DIM) ? 1.0f : 0.0f;
                acc += (wq * fl2) *
                       __builtin_amdgcn_exp2f(fmaf(imw, C10L2E, c2));
            }
        }
    };

    // ---- row y0 (buf A): centers for cr=0; dy=0 right-only taps ----
#pragma unroll
    for (int i = 0; i < 4; ++i) {
        ic0[0][i] = A[0][3 + i]; ic1[0][i] = A[1][3 + i]; ic2[0][i] = A[2][3 + i];
        fc0[0][i] = A[3][3 + i]; fc1[0][i] = A[4][3 + i];
    }
    tap_row(0, A, 0, 1, true);
    LOAD_ROW(A, y0 + 2);                       // A free -> prefetch row y0+2

    // ---- row y0+1 (buf B): centers for cr=1; dy0(cr1) + dy1(cr0) ----
#pragma unroll
    for (int i = 0; i < 4; ++i) {
        ic0[1][i] = B[0][3 + i]; ic1[1][i] = B[1][3 + i]; ic2[1][i] = B[2][3 + i];
        fc0[1][i] = B[3][3 + i]; fc1[1][i] = B[4][3 + i];
    }
    tap_row(1, B, 0, 1, true);
    tap_row(0, B, 1, -3, true);
    LOAD_ROW(B, y0 + 3);                       // B free -> prefetch row y0+3

    // ---- row y0+2 (buf A): dy2(cr0) + dy1(cr1) ----
    {
        const bool yin = (y0 + 2) < S_DIM;
        tap_row(0, A, 2, -3, yin);
        tap_row(1, A, 1, -3, yin);
    }
    LOAD_ROW(A, y0 + 4);                       // A free -> prefetch row y0+4

    // ---- row y0+3 (buf B): dy3(cr0) + dy2(cr1) ----
    {
        const bool yin = (y0 + 3) < S_DIM;
        tap_row(0, B, 3, -3, yin);
        tap_row(1, B, 2, -3, yin);
    }

    // ---- row y0+4 (buf A): dy3(cr1) ----
    tap_row(1, A, 3, -3, (y0 + 4) < S_DIM);

    // ---- OOB taps: n_oob(x,y) identical terms per pixel, both rows ----
    float oob = 0.0f;
#pragma unroll
    for (int cr = 0; cr < 2; ++cr) {
        const int yg = y0 + cr;
        const int ny_in = 7 - max(0, 3 - yg) - max(0, yg - (S_DIM - 1 - 3));
        const float gyc = -1.0f + step * (float)yg;
#pragma unroll
        for (int i = 0; i < 4; ++i) {
            const int xg = x0 + i;
            const int nx_in = 7 - max(0, 3 - xg) - max(0, xg - (S_DIM - 1 - 3));
            const float n_oob = (float)(49 - ny_in * nx_in);
            const float gxc = -1.0f + step * (float)xg;
            const float g2c = gyc * gyc + gxc * gxc;
            const float imw_c = ic0[cr][i] * ic0[cr][i] +
                                ic1[cr][i] * ic1[cr][i] +
                                ic2[cr][i] * ic2[cr][i];
            const float fl_c = fc0[cr][i] * fc0[cr][i] +
                               fc1[cr][i] * fc1[cr][i];
            oob += (n_oob * fl_c) *
                   __builtin_amdgcn_exp2f(fmaf(imw_c, C10L2E, -g2c * LOG2E));
        }
    }

    // ---- block reduction -> per-block partial ----
    float acc_all = 2.0f * acc + oob;
#pragma unroll
    for (int off = 32; off > 0; off >>= 1)
        acc_all += __shfl_down(acc_all, off, 64);
    if (lane == 0) wave_sums[wv] = acc_all;
    __syncthreads();
    if (lane == 0 && wv == 0) {
        partial[blockIdx.z * gridDim.x + blockIdx.x] =
            (wave_sums[0] + wave_sums[1]) + (wave_sums[2] + wave_sums[3]);
    }
}

__global__ __launch_bounds__(256) void reduce_kernel(
    const float* __restrict__ partial, float* __restrict__ out)
{
    __shared__ float wave_sums[4];
    const int t = threadIdx.x;
    typedef float v2f __attribute__((ext_vector_type(2)));
    const v2f v = ((const v2f*)partial)[t];      // 512 floats = 256 v2f
    float s = v.x + v.y;
#pragma unroll
    for (int off = 32; off > 0; off >>= 1)
        s += __shfl_down(s, off, 64);
    if ((t & 63) == 0) wave_sums[t >> 6] = s;
    __syncthreads();
    if (t == 0) {
        out[0] = ((wave_sums[0] + wave_sums[1]) + (wave_sums[2] + wave_sums[3]))
                 * FINAL_SCALE;
    }
}

extern "C" void kernel_launch(void* const* d_in, const int* in_sizes, int n_in,
                              void* d_out, int out_size, void* d_ws, size_t ws_size,
                              hipStream_t stream) {
    const float* flow  = (const float*)d_in[0];
    const float* image = (const float*)d_in[1];
    float* out = (float*)d_out;
    float* partial = (float*)d_ws;

    dim3 grid(32, 1, 16);     // 32 blocks x 4 waves = 128 row-pairs; x16 batch
    dim3 block(64, 4);        // one wave per row-pair
    flow_reg_loss_kernel<<<grid, block, 0, stream>>>(flow, image, partial);
    reduce_kernel<<<1, 256, 0, stream>>>(partial, out);
}